// Round 1
// baseline (7932.457 us; speedup 1.0000x reference)
//
#include <hip/hip_runtime.h>
#include <hip/hip_bf16.h>

#define N_NODES  100000
#define N_EDGES  300000
#define FEAT     256
#define N_GRAPHS 500
#define N_LAYERS 6

typedef __attribute__((ext_vector_type(8))) short v8s;   // 8 x bf16 bits (4 VGPRs)
typedef __attribute__((ext_vector_type(4))) float v4f;   // MFMA accumulator

__device__ __forceinline__ unsigned short f2bf(float f) {
    unsigned u = __float_as_uint(f);
    unsigned r = u + 0x7fffu + ((u >> 16) & 1u);   // RNE
    return (unsigned short)(r >> 16);
}
__device__ __forceinline__ float bf2f(unsigned short b) {
    return __uint_as_float(((unsigned)b) << 16);
}

// ---- init: copy x -> xf (f32 residual), convert -> xb (bf16) ----
__global__ __launch_bounds__(256) void init_kernel(const float* __restrict__ x,
                                                   float* __restrict__ xf,
                                                   ushort* __restrict__ xb) {
    int i = blockIdx.x * 256 + threadIdx.x;           // per 4 elements
    if ((size_t)i * 4 >= (size_t)N_NODES * FEAT) return;
    float4 v = ((const float4*)x)[i];
    ((float4*)xf)[i] = v;
    ushort4 b = make_ushort4(f2bf(v.x), f2bf(v.y), f2bf(v.z), f2bf(v.w));
    ((ushort4*)xb)[i] = b;
}

// ---- weights f32 -> bf16, all layers at once ----
__global__ __launch_bounds__(256) void wconv_kernel(const float* __restrict__ Wl,
                                                    const float* __restrict__ Wr,
                                                    ushort* __restrict__ wlb,
                                                    ushort* __restrict__ wrb) {
    int i = blockIdx.x * 256 + threadIdx.x;           // per 4 elements
    if ((size_t)i * 4 >= (size_t)N_LAYERS * FEAT * FEAT) return;
    float4 a = ((const float4*)Wl)[i];
    float4 b = ((const float4*)Wr)[i];
    ((ushort4*)wlb)[i] = make_ushort4(f2bf(a.x), f2bf(a.y), f2bf(a.z), f2bf(a.w));
    ((ushort4*)wrb)[i] = make_ushort4(f2bf(b.x), f2bf(b.y), f2bf(b.z), f2bf(b.w));
}

// ---- in-degree histogram (deg as float) ----
__global__ __launch_bounds__(256) void deg_kernel(const int* __restrict__ dst,
                                                  float* __restrict__ deg) {
    int e = blockIdx.x * 256 + threadIdx.x;
    if (e < N_EDGES) atomicAdd(&deg[dst[e]], 1.0f);
}

// ---- per-graph [start,end) bounds from sorted batch ----
__global__ __launch_bounds__(256) void bounds_kernel(const int* __restrict__ batch,
                                                     unsigned* __restrict__ gs,
                                                     unsigned* __restrict__ ge) {
    int i = blockIdx.x * 256 + threadIdx.x;
    if (i >= N_NODES) return;
    int g = batch[i];
    atomicMin(&gs[g], (unsigned)i);
    atomicMax(&ge[g], (unsigned)(i + 1));
}

// ---- edge aggregation: one wave per edge, 4 bf16 feats per lane ----
__global__ __launch_bounds__(256) void agg_kernel(const int* __restrict__ ei,
                                                  const ushort* __restrict__ xb,
                                                  float* __restrict__ msg) {
    int eid = blockIdx.x * 4 + (threadIdx.x >> 6);
    int lane = threadIdx.x & 63;
    if (eid >= N_EDGES) return;
    int src = ei[eid];
    int dst = ei[N_EDGES + eid];
    ushort4 v = *(const ushort4*)(xb + (size_t)src * FEAT + lane * 4);
    float* m = msg + (size_t)dst * FEAT + lane * 4;
    atomicAdd(m + 0, bf2f(v.x));
    atomicAdd(m + 1, bf2f(v.y));
    atomicAdd(m + 2, bf2f(v.z));
    atomicAdd(m + 3, bf2f(v.w));
}

// ---- mean = msg / max(deg,1), convert to bf16 ----
__global__ __launch_bounds__(256) void mean_kernel(const float* __restrict__ msg,
                                                   const float* __restrict__ deg,
                                                   ushort* __restrict__ meanb) {
    int i = blockIdx.x * 256 + threadIdx.x;           // per 4 elements
    if ((size_t)i * 4 >= (size_t)N_NODES * FEAT) return;
    int node = i >> 6;                                 // (i*4)/256
    float r = 1.0f / fmaxf(deg[node], 1.0f);
    float4 v = ((const float4*)msg)[i];
    ((ushort4*)meanb)[i] = make_ushort4(f2bf(v.x * r), f2bf(v.y * r),
                                        f2bf(v.z * r), f2bf(v.w * r));
}

// ---- fused GEMM: y = relu(mean@Wl^T + bl + x@Wr^T) + x  (128x128 tile, 4 waves) ----
__global__ __launch_bounds__(256) void gemm_kernel(const ushort* __restrict__ A0,   // meanb
                                                   const ushort* __restrict__ A1,   // xb_cur
                                                   const ushort* __restrict__ B0,   // Wl slice [256][256]
                                                   const ushort* __restrict__ B1,   // Wr slice
                                                   const float* __restrict__ bias,  // bl slice [256]
                                                   float* __restrict__ xf,          // residual in/out
                                                   ushort* __restrict__ xbn) {      // next-layer bf16 x
    const int lane = threadIdx.x & 63;
    const int wid  = threadIdx.x >> 6;
    const int wr = wid >> 1, wc = wid & 1;             // 2x2 waves, 64x64 each
    const int row0 = blockIdx.x * 128 + wr * 64;
    const int col0 = blockIdx.y * 128 + wc * 64;
    const int lr = lane & 15;
    const int lk = (lane >> 4) * 8;

    v4f acc[4][4];
    #pragma unroll
    for (int i = 0; i < 4; i++)
        #pragma unroll
        for (int j = 0; j < 4; j++) acc[i][j] = (v4f){0.f, 0.f, 0.f, 0.f};

    int arow[4], bcol[4];
    #pragma unroll
    for (int i = 0; i < 4; i++) {
        int r = row0 + i * 16 + lr;
        arow[i] = (r < N_NODES) ? r : 0;               // clamp; guarded at store
        bcol[i] = col0 + i * 16 + lr;                  // always < 256
    }

    #pragma unroll 1
    for (int half = 0; half < 2; ++half) {
        const ushort* A = half ? A1 : A0;
        const ushort* B = half ? B1 : B0;
        #pragma unroll 1
        for (int k = 0; k < 256; k += 32) {
            v8s a[4], b[4];
            #pragma unroll
            for (int i = 0; i < 4; i++)
                a[i] = *(const v8s*)(A + (size_t)arow[i] * FEAT + k + lk);
            #pragma unroll
            for (int j = 0; j < 4; j++)
                b[j] = *(const v8s*)(B + (size_t)bcol[j] * FEAT + k + lk);
            #pragma unroll
            for (int i = 0; i < 4; i++)
                #pragma unroll
                for (int j = 0; j < 4; j++)
                    acc[i][j] = __builtin_amdgcn_mfma_f32_16x16x32_bf16(a[i], b[j], acc[i][j], 0, 0, 0);
        }
    }

    // epilogue: C/D layout col=lane&15, row=(lane>>4)*4+reg
    const int orow = (lane >> 4) * 4;
    const int ocol = lane & 15;
    #pragma unroll
    for (int j = 0; j < 4; j++) {
        int col = col0 + j * 16 + ocol;
        float bv = bias[col];
        #pragma unroll
        for (int i = 0; i < 4; i++) {
            #pragma unroll
            for (int r = 0; r < 4; r++) {
                int row = row0 + i * 16 + orow + r;
                if (row < N_NODES) {
                    float v = fmaxf(acc[i][j][r] + bv, 0.0f);
                    size_t idx = (size_t)row * FEAT + col;
                    float res = xf[idx] + v;
                    xf[idx] = res;
                    xbn[idx] = f2bf(res);
                }
            }
        }
    }
}

// ---- per-graph per-feature online softmax aggregation ----
__global__ __launch_bounds__(256) void smax_kernel(const float* __restrict__ xf,
                                                   const unsigned* __restrict__ gs,
                                                   const unsigned* __restrict__ ge,
                                                   const float* __restrict__ t,
                                                   float* __restrict__ out) {
    int g = blockIdx.x;
    int f = threadIdx.x;
    unsigned s = gs[g], e = ge[g];
    float tv = t[0];
    float m = -INFINITY, den = 0.f, acc = 0.f;
    if (s < e) {
        for (unsigned n = s; n < e; ++n) {
            float xv = xf[(size_t)n * FEAT + f];
            float sc = tv * xv;
            float mn = fmaxf(m, sc);
            float scale = expf(m - mn);     // 0 on first iter (m = -inf)
            float w = expf(sc - mn);
            den = den * scale + w;
            acc = acc * scale + w * xv;
            m = mn;
        }
        out[(size_t)g * FEAT + f] = acc / fmaxf(den, 1e-16f);
    } else {
        out[(size_t)g * FEAT + f] = 0.f;   // empty segment -> 0 per reference
    }
}

extern "C" void kernel_launch(void* const* d_in, const int* in_sizes, int n_in,
                              void* d_out, int out_size, void* d_ws, size_t ws_size,
                              hipStream_t stream) {
    const float* x     = (const float*)d_in[0];
    const int*   ei    = (const int*)d_in[1];    // [2, E]: row0=src, row1=dst
    const int*   batch = (const int*)d_in[2];
    const float* Wl    = (const float*)d_in[3];  // [L, F, F]
    const float* bl    = (const float*)d_in[4];  // [L, F]
    const float* Wr    = (const float*)d_in[5];  // [L, F, F]
    const float* t     = (const float*)d_in[6];  // [1]
    float* out = (float*)d_out;

    const size_t NF4 = (size_t)N_NODES * FEAT * 4;   // 102,400,000
    const size_t NF2 = (size_t)N_NODES * FEAT * 2;   //  51,200,000
    char* ws = (char*)d_ws;
    float*  msg   = (float*)(ws);
    float*  xf    = (float*)(ws + NF4);
    ushort* xb0   = (ushort*)(ws + 2 * NF4);
    ushort* xb1   = (ushort*)(ws + 2 * NF4 + NF2);
    ushort* meanb = (ushort*)(ws + 2 * NF4 + 2 * NF2);
    ushort* wlb   = (ushort*)(ws + 2 * NF4 + 3 * NF2);
    ushort* wrb   = (ushort*)(ws + 2 * NF4 + 3 * NF2 + (size_t)N_LAYERS * FEAT * FEAT * 2);
    float*  deg   = (float*)(ws + 2 * NF4 + 3 * NF2 + 2 * (size_t)N_LAYERS * FEAT * FEAT * 2);
    unsigned* gs  = (unsigned*)((char*)deg + (size_t)N_NODES * 4);
    unsigned* ge  = gs + N_GRAPHS;

    hipMemsetAsync(deg, 0, (size_t)N_NODES * 4, stream);
    hipMemsetAsync(gs, 0xFF, (size_t)N_GRAPHS * 4, stream);
    hipMemsetAsync(ge, 0, (size_t)N_GRAPHS * 4, stream);

    init_kernel<<<(N_NODES * FEAT / 4 + 255) / 256, 256, 0, stream>>>(x, xf, xb0);
    wconv_kernel<<<(N_LAYERS * FEAT * FEAT / 4 + 255) / 256, 256, 0, stream>>>(Wl, Wr, wlb, wrb);
    deg_kernel<<<(N_EDGES + 255) / 256, 256, 0, stream>>>(ei + N_EDGES, deg);
    bounds_kernel<<<(N_NODES + 255) / 256, 256, 0, stream>>>(batch, gs, ge);

    ushort* cur = xb0;
    ushort* nxt = xb1;
    for (int l = 0; l < N_LAYERS; ++l) {
        hipMemsetAsync(msg, 0, NF4, stream);
        agg_kernel<<<N_EDGES / 4, 256, 0, stream>>>(ei, cur, msg);
        mean_kernel<<<(N_NODES * FEAT / 4 + 255) / 256, 256, 0, stream>>>(msg, deg, meanb);
        gemm_kernel<<<dim3((N_NODES + 127) / 128, FEAT / 128), 256, 0, stream>>>(
            meanb, cur,
            wlb + (size_t)l * FEAT * FEAT, wrb + (size_t)l * FEAT * FEAT,
            bl + (size_t)l * FEAT, xf, nxt);
        ushort* tmp = cur; cur = nxt; nxt = tmp;
    }

    smax_kernel<<<N_GRAPHS, 256, 0, stream>>>(xf, gs, ge, t, out);
}

// Round 2
// 1626.747 us; speedup vs baseline: 4.8763x; 4.8763x over previous
//
#include <hip/hip_runtime.h>
#include <hip/hip_bf16.h>

#define N_NODES  100000
#define N_EDGES  300000
#define FEAT     256
#define N_GRAPHS 500
#define N_LAYERS 6
#define SCAN_B   1024

typedef __attribute__((ext_vector_type(8))) short v8s;   // 8 x bf16 bits (4 VGPRs)
typedef __attribute__((ext_vector_type(4))) float v4f;   // MFMA accumulator

__device__ __forceinline__ unsigned short f2bf(float f) {
    unsigned u = __float_as_uint(f);
    unsigned r = u + 0x7fffu + ((u >> 16) & 1u);   // RNE
    return (unsigned short)(r >> 16);
}
__device__ __forceinline__ float bf2f(unsigned short b) {
    return __uint_as_float(((unsigned)b) << 16);
}

// ---- init: copy x -> xf (f32 residual), convert -> xb (bf16) ----
__global__ __launch_bounds__(256) void init_kernel(const float* __restrict__ x,
                                                   float* __restrict__ xf,
                                                   ushort* __restrict__ xb) {
    int i = blockIdx.x * 256 + threadIdx.x;           // per 4 elements
    if ((size_t)i * 4 >= (size_t)N_NODES * FEAT) return;
    float4 v = ((const float4*)x)[i];
    ((float4*)xf)[i] = v;
    ushort4 b = make_ushort4(f2bf(v.x), f2bf(v.y), f2bf(v.z), f2bf(v.w));
    ((ushort4*)xb)[i] = b;
}

// ---- weights f32 -> bf16, all layers at once ----
__global__ __launch_bounds__(256) void wconv_kernel(const float* __restrict__ Wl,
                                                    const float* __restrict__ Wr,
                                                    ushort* __restrict__ wlb,
                                                    ushort* __restrict__ wrb) {
    int i = blockIdx.x * 256 + threadIdx.x;           // per 4 elements
    if ((size_t)i * 4 >= (size_t)N_LAYERS * FEAT * FEAT) return;
    float4 a = ((const float4*)Wl)[i];
    float4 b = ((const float4*)Wr)[i];
    ((ushort4*)wlb)[i] = make_ushort4(f2bf(a.x), f2bf(a.y), f2bf(a.z), f2bf(a.w));
    ((ushort4*)wrb)[i] = make_ushort4(f2bf(b.x), f2bf(b.y), f2bf(b.z), f2bf(b.w));
}

// ================= CSR construction (counting sort by dst) =================

__global__ __launch_bounds__(256) void hist_kernel(const int* __restrict__ dst,
                                                   unsigned* __restrict__ degu) {
    int e = blockIdx.x * 256 + threadIdx.x;
    if (e < N_EDGES) atomicAdd(&degu[dst[e]], 1u);
}

// per-block inclusive scan -> exclusive partials + block sums
__global__ __launch_bounds__(SCAN_B) void scan_blocks(const unsigned* __restrict__ degu,
                                                      unsigned* __restrict__ excl,
                                                      unsigned* __restrict__ bsum) {
    __shared__ unsigned tmp[SCAN_B];
    int i = blockIdx.x * SCAN_B + threadIdx.x;
    unsigned v = (i < N_NODES) ? degu[i] : 0u;
    tmp[threadIdx.x] = v;
    __syncthreads();
    for (int off = 1; off < SCAN_B; off <<= 1) {
        unsigned add = (threadIdx.x >= off) ? tmp[threadIdx.x - off] : 0u;
        __syncthreads();
        tmp[threadIdx.x] += add;
        __syncthreads();
    }
    if (i < N_NODES) excl[i] = tmp[threadIdx.x] - v;
    if (threadIdx.x == SCAN_B - 1) bsum[blockIdx.x] = tmp[SCAN_B - 1];
}

// serial scan of block sums (nb ~ 98, trivial)
__global__ void scan_tops(unsigned* __restrict__ bsum, int nb) {
    unsigned run = 0;
    for (int b = 0; b < nb; ++b) { unsigned t = bsum[b]; bsum[b] = run; run += t; }
}

__global__ __launch_bounds__(256) void finalize_rowptr(const unsigned* __restrict__ excl,
                                                       const unsigned* __restrict__ bsum,
                                                       unsigned* __restrict__ rowptr,
                                                       unsigned* __restrict__ cursor) {
    int i = blockIdx.x * 256 + threadIdx.x;
    if (i < N_NODES) {
        unsigned v = excl[i] + bsum[i / SCAN_B];
        rowptr[i] = v;
        cursor[i] = v;
    }
    if (i == N_NODES) rowptr[N_NODES] = N_EDGES;
}

__global__ __launch_bounds__(256) void scatter_kernel(const int* __restrict__ ei,
                                                      unsigned* __restrict__ cursor,
                                                      unsigned* __restrict__ col) {
    int e = blockIdx.x * 256 + threadIdx.x;
    if (e >= N_EDGES) return;
    int d = ei[N_EDGES + e];
    unsigned p = atomicAdd(&cursor[d], 1u);
    col[p] = (unsigned)ei[e];
}

// ---- per-graph [start,end) bounds from sorted batch ----
__global__ __launch_bounds__(256) void bounds_kernel(const int* __restrict__ batch,
                                                     unsigned* __restrict__ gs,
                                                     unsigned* __restrict__ ge) {
    int i = blockIdx.x * 256 + threadIdx.x;
    if (i >= N_NODES) return;
    int g = batch[i];
    atomicMin(&gs[g], (unsigned)i);
    atomicMax(&ge[g], (unsigned)(i + 1));
}

// ---- CSR mean-aggregate: one wave per node, 4 feats/lane, no atomics ----
__global__ __launch_bounds__(256) void agg_csr(const unsigned* __restrict__ rowptr,
                                               const unsigned* __restrict__ col,
                                               const ushort* __restrict__ xb,
                                               ushort* __restrict__ meanb) {
    int node = blockIdx.x * 4 + (threadIdx.x >> 6);
    int lane = threadIdx.x & 63;
    if (node >= N_NODES) return;
    unsigned s = rowptr[node], e = rowptr[node + 1];
    float a0 = 0.f, a1 = 0.f, a2 = 0.f, a3 = 0.f;
    for (unsigned j = s; j < e; ++j) {
        unsigned src = col[j];
        ushort4 v = *(const ushort4*)(xb + (size_t)src * FEAT + lane * 4);
        a0 += bf2f(v.x); a1 += bf2f(v.y); a2 += bf2f(v.z); a3 += bf2f(v.w);
    }
    float r = 1.0f / fmaxf((float)(e - s), 1.0f);
    ushort4 o = make_ushort4(f2bf(a0 * r), f2bf(a1 * r), f2bf(a2 * r), f2bf(a3 * r));
    *(ushort4*)(meanb + (size_t)node * FEAT + lane * 4) = o;
}

// ---- fused GEMM: y = relu(mean@Wl^T + bl + x@Wr^T) + x  (128x128 tile, 4 waves) ----
__global__ __launch_bounds__(256) void gemm_kernel(const ushort* __restrict__ A0,   // meanb
                                                   const ushort* __restrict__ A1,   // xb_cur
                                                   const ushort* __restrict__ B0,   // Wl slice [256][256]
                                                   const ushort* __restrict__ B1,   // Wr slice
                                                   const float* __restrict__ bias,  // bl slice [256]
                                                   float* __restrict__ xf,          // residual in/out
                                                   ushort* __restrict__ xbn) {      // next-layer bf16 x
    const int lane = threadIdx.x & 63;
    const int wid  = threadIdx.x >> 6;
    const int wr = wid >> 1, wc = wid & 1;             // 2x2 waves, 64x64 each
    const int row0 = blockIdx.x * 128 + wr * 64;
    const int col0 = blockIdx.y * 128 + wc * 64;
    const int lr = lane & 15;
    const int lk = (lane >> 4) * 8;

    v4f acc[4][4];
    #pragma unroll
    for (int i = 0; i < 4; i++)
        #pragma unroll
        for (int j = 0; j < 4; j++) acc[i][j] = (v4f){0.f, 0.f, 0.f, 0.f};

    int arow[4], bcol[4];
    #pragma unroll
    for (int i = 0; i < 4; i++) {
        int r = row0 + i * 16 + lr;
        arow[i] = (r < N_NODES) ? r : 0;               // clamp; guarded at store
        bcol[i] = col0 + i * 16 + lr;                  // always < 256
    }

    #pragma unroll 1
    for (int half = 0; half < 2; ++half) {
        const ushort* A = half ? A1 : A0;
        const ushort* B = half ? B1 : B0;
        #pragma unroll 1
        for (int k = 0; k < 256; k += 32) {
            v8s a[4], b[4];
            #pragma unroll
            for (int i = 0; i < 4; i++)
                a[i] = *(const v8s*)(A + (size_t)arow[i] * FEAT + k + lk);
            #pragma unroll
            for (int j = 0; j < 4; j++)
                b[j] = *(const v8s*)(B + (size_t)bcol[j] * FEAT + k + lk);
            #pragma unroll
            for (int i = 0; i < 4; i++)
                #pragma unroll
                for (int j = 0; j < 4; j++)
                    acc[i][j] = __builtin_amdgcn_mfma_f32_16x16x32_bf16(a[i], b[j], acc[i][j], 0, 0, 0);
        }
    }

    // epilogue: C/D layout col=lane&15, row=(lane>>4)*4+reg
    const int orow = (lane >> 4) * 4;
    const int ocol = lane & 15;
    #pragma unroll
    for (int j = 0; j < 4; j++) {
        int col = col0 + j * 16 + ocol;
        float bv = bias[col];
        #pragma unroll
        for (int i = 0; i < 4; i++) {
            #pragma unroll
            for (int r = 0; r < 4; r++) {
                int row = row0 + i * 16 + orow + r;
                if (row < N_NODES) {
                    float v = fmaxf(acc[i][j][r] + bv, 0.0f);
                    size_t idx = (size_t)row * FEAT + col;
                    float res = xf[idx] + v;
                    xf[idx] = res;
                    xbn[idx] = f2bf(res);
                }
            }
        }
    }
}

// ---- per-graph per-feature online softmax aggregation ----
__global__ __launch_bounds__(256) void smax_kernel(const float* __restrict__ xf,
                                                   const unsigned* __restrict__ gs,
                                                   const unsigned* __restrict__ ge,
                                                   const float* __restrict__ t,
                                                   float* __restrict__ out) {
    int g = blockIdx.x;
    int f = threadIdx.x;
    unsigned s = gs[g], e = ge[g];
    float tv = t[0];
    float m = -INFINITY, den = 0.f, acc = 0.f;
    if (s < e) {
        for (unsigned n = s; n < e; ++n) {
            float xv = xf[(size_t)n * FEAT + f];
            float sc = tv * xv;
            float mn = fmaxf(m, sc);
            float scale = expf(m - mn);     // 0 on first iter (m = -inf)
            float w = expf(sc - mn);
            den = den * scale + w;
            acc = acc * scale + w * xv;
            m = mn;
        }
        out[(size_t)g * FEAT + f] = acc / fmaxf(den, 1e-16f);
    } else {
        out[(size_t)g * FEAT + f] = 0.f;   // empty segment -> 0 per reference
    }
}

extern "C" void kernel_launch(void* const* d_in, const int* in_sizes, int n_in,
                              void* d_out, int out_size, void* d_ws, size_t ws_size,
                              hipStream_t stream) {
    const float* x     = (const float*)d_in[0];
    const int*   ei    = (const int*)d_in[1];    // [2, E]: row0=src, row1=dst
    const int*   batch = (const int*)d_in[2];
    const float* Wl    = (const float*)d_in[3];  // [L, F, F]
    const float* bl    = (const float*)d_in[4];  // [L, F]
    const float* Wr    = (const float*)d_in[5];  // [L, F, F]
    const float* t     = (const float*)d_in[6];  // [1]
    float* out = (float*)d_out;

    const size_t NF4 = (size_t)N_NODES * FEAT * 4;   // 102,400,000
    const size_t NF2 = (size_t)N_NODES * FEAT * 2;   //  51,200,000
    const size_t WSZ = (size_t)N_LAYERS * FEAT * FEAT * 2;

    char* ws = (char*)d_ws;
    size_t off = 0;
    float*  xf    = (float*)(ws + off);  off += NF4;
    ushort* xb0   = (ushort*)(ws + off); off += NF2;
    ushort* xb1   = (ushort*)(ws + off); off += NF2;
    ushort* meanb = (ushort*)(ws + off); off += NF2;
    ushort* wlb   = (ushort*)(ws + off); off += WSZ;
    ushort* wrb   = (ushort*)(ws + off); off += WSZ;
    unsigned* degu   = (unsigned*)(ws + off); off += (size_t)N_NODES * 4;
    unsigned* excl   = (unsigned*)(ws + off); off += (size_t)N_NODES * 4;
    unsigned* bsum   = (unsigned*)(ws + off); off += 128 * 4;
    unsigned* rowptr = (unsigned*)(ws + off); off += (size_t)(N_NODES + 1) * 4;
    unsigned* cursor = (unsigned*)(ws + off); off += (size_t)N_NODES * 4;
    unsigned* col    = (unsigned*)(ws + off); off += (size_t)N_EDGES * 4;
    unsigned* gs     = (unsigned*)(ws + off); off += (size_t)N_GRAPHS * 4;
    unsigned* ge     = (unsigned*)(ws + off); off += (size_t)N_GRAPHS * 4;

    hipMemsetAsync(degu, 0, (size_t)N_NODES * 4, stream);
    hipMemsetAsync(gs, 0xFF, (size_t)N_GRAPHS * 4, stream);
    hipMemsetAsync(ge, 0, (size_t)N_GRAPHS * 4, stream);

    init_kernel<<<(N_NODES * FEAT / 4 + 255) / 256, 256, 0, stream>>>(x, xf, xb0);
    wconv_kernel<<<(N_LAYERS * FEAT * FEAT / 4 + 255) / 256, 256, 0, stream>>>(Wl, Wr, wlb, wrb);

    // CSR build
    const int NB_SCAN = (N_NODES + SCAN_B - 1) / SCAN_B;   // 98
    hist_kernel<<<(N_EDGES + 255) / 256, 256, 0, stream>>>(ei + N_EDGES, degu);
    scan_blocks<<<NB_SCAN, SCAN_B, 0, stream>>>(degu, excl, bsum);
    scan_tops<<<1, 1, 0, stream>>>(bsum, NB_SCAN);
    finalize_rowptr<<<(N_NODES + 256) / 256, 256, 0, stream>>>(excl, bsum, rowptr, cursor);
    scatter_kernel<<<(N_EDGES + 255) / 256, 256, 0, stream>>>(ei, cursor, col);

    bounds_kernel<<<(N_NODES + 255) / 256, 256, 0, stream>>>(batch, gs, ge);

    ushort* cur = xb0;
    ushort* nxt = xb1;
    for (int l = 0; l < N_LAYERS; ++l) {
        agg_csr<<<(N_NODES + 3) / 4, 256, 0, stream>>>(rowptr, col, cur, meanb);
        gemm_kernel<<<dim3((N_NODES + 127) / 128, FEAT / 128), 256, 0, stream>>>(
            meanb, cur,
            wlb + (size_t)l * FEAT * FEAT, wrb + (size_t)l * FEAT * FEAT,
            bl + (size_t)l * FEAT, xf, nxt);
        ushort* tmp = cur; cur = nxt; nxt = tmp;
    }

    smax_kernel<<<N_GRAPHS, 256, 0, stream>>>(xf, gs, ge, t, out);
}

// Round 3
// 1015.648 us; speedup vs baseline: 7.8102x; 1.6017x over previous
//
#include <hip/hip_runtime.h>
#include <hip/hip_bf16.h>

#define N_NODES  100000
#define N_EDGES  300000
#define FEAT     256
#define N_GRAPHS 500
#define N_LAYERS 6
#define SCAN_B   1024

typedef __attribute__((ext_vector_type(8))) short v8s;   // 8 x bf16 bits (4 VGPRs)
typedef __attribute__((ext_vector_type(4))) float v4f;   // MFMA accumulator

__device__ __forceinline__ unsigned short f2bf(float f) {
    unsigned u = __float_as_uint(f);
    unsigned r = u + 0x7fffu + ((u >> 16) & 1u);   // RNE
    return (unsigned short)(r >> 16);
}
__device__ __forceinline__ float bf2f(unsigned short b) {
    return __uint_as_float(((unsigned)b) << 16);
}

__device__ __forceinline__ void gload16(const ushort* g, ushort* l) {
    __builtin_amdgcn_global_load_lds((const __attribute__((address_space(1))) void*)g,
                                     (__attribute__((address_space(3))) void*)l,
                                     16, 0, 0);
}

// ---- init: x (f32) -> xb (bf16). No f32 residual buffer anymore. ----
__global__ __launch_bounds__(256) void init_kernel(const float* __restrict__ x,
                                                   ushort* __restrict__ xb) {
    int i = blockIdx.x * 256 + threadIdx.x;           // per 4 elements
    if ((size_t)i * 4 >= (size_t)N_NODES * FEAT) return;
    float4 v = ((const float4*)x)[i];
    ((ushort4*)xb)[i] = make_ushort4(f2bf(v.x), f2bf(v.y), f2bf(v.z), f2bf(v.w));
}

// ---- weights f32 -> bf16, all layers at once ----
__global__ __launch_bounds__(256) void wconv_kernel(const float* __restrict__ Wl,
                                                    const float* __restrict__ Wr,
                                                    ushort* __restrict__ wlb,
                                                    ushort* __restrict__ wrb) {
    int i = blockIdx.x * 256 + threadIdx.x;           // per 4 elements
    if ((size_t)i * 4 >= (size_t)N_LAYERS * FEAT * FEAT) return;
    float4 a = ((const float4*)Wl)[i];
    float4 b = ((const float4*)Wr)[i];
    ((ushort4*)wlb)[i] = make_ushort4(f2bf(a.x), f2bf(a.y), f2bf(a.z), f2bf(a.w));
    ((ushort4*)wrb)[i] = make_ushort4(f2bf(b.x), f2bf(b.y), f2bf(b.z), f2bf(b.w));
}

// ================= CSR construction (counting sort by dst) =================

__global__ __launch_bounds__(256) void hist_kernel(const int* __restrict__ dst,
                                                   unsigned* __restrict__ degu) {
    int e = blockIdx.x * 256 + threadIdx.x;
    if (e < N_EDGES) atomicAdd(&degu[dst[e]], 1u);
}

__global__ __launch_bounds__(SCAN_B) void scan_blocks(const unsigned* __restrict__ degu,
                                                      unsigned* __restrict__ excl,
                                                      unsigned* __restrict__ bsum) {
    __shared__ unsigned tmp[SCAN_B];
    int i = blockIdx.x * SCAN_B + threadIdx.x;
    unsigned v = (i < N_NODES) ? degu[i] : 0u;
    tmp[threadIdx.x] = v;
    __syncthreads();
    for (int off = 1; off < SCAN_B; off <<= 1) {
        unsigned add = (threadIdx.x >= off) ? tmp[threadIdx.x - off] : 0u;
        __syncthreads();
        tmp[threadIdx.x] += add;
        __syncthreads();
    }
    if (i < N_NODES) excl[i] = tmp[threadIdx.x] - v;
    if (threadIdx.x == SCAN_B - 1) bsum[blockIdx.x] = tmp[SCAN_B - 1];
}

__global__ void scan_tops(unsigned* __restrict__ bsum, int nb) {
    unsigned run = 0;
    for (int b = 0; b < nb; ++b) { unsigned t = bsum[b]; bsum[b] = run; run += t; }
}

__global__ __launch_bounds__(256) void finalize_rowptr(const unsigned* __restrict__ excl,
                                                       const unsigned* __restrict__ bsum,
                                                       unsigned* __restrict__ rowptr,
                                                       unsigned* __restrict__ cursor) {
    int i = blockIdx.x * 256 + threadIdx.x;
    if (i < N_NODES) {
        unsigned v = excl[i] + bsum[i / SCAN_B];
        rowptr[i] = v;
        cursor[i] = v;
    }
    if (i == N_NODES) rowptr[N_NODES] = N_EDGES;
}

__global__ __launch_bounds__(256) void scatter_kernel(const int* __restrict__ ei,
                                                      unsigned* __restrict__ cursor,
                                                      unsigned* __restrict__ col) {
    int e = blockIdx.x * 256 + threadIdx.x;
    if (e >= N_EDGES) return;
    int d = ei[N_EDGES + e];
    unsigned p = atomicAdd(&cursor[d], 1u);
    col[p] = (unsigned)ei[e];
}

// ---- per-graph [start,end) bounds from sorted batch ----
__global__ __launch_bounds__(256) void bounds_kernel(const int* __restrict__ batch,
                                                     unsigned* __restrict__ gs,
                                                     unsigned* __restrict__ ge) {
    int i = blockIdx.x * 256 + threadIdx.x;
    if (i >= N_NODES) return;
    int g = batch[i];
    atomicMin(&gs[g], (unsigned)i);
    atomicMax(&ge[g], (unsigned)(i + 1));
}

// ---- CSR mean-aggregate: one wave per node, 4 feats/lane, no atomics ----
__global__ __launch_bounds__(256) void agg_csr(const unsigned* __restrict__ rowptr,
                                               const unsigned* __restrict__ col,
                                               const ushort* __restrict__ xb,
                                               ushort* __restrict__ meanb) {
    int node = blockIdx.x * 4 + (threadIdx.x >> 6);
    int lane = threadIdx.x & 63;
    if (node >= N_NODES) return;
    unsigned s = rowptr[node], e = rowptr[node + 1];
    float a0 = 0.f, a1 = 0.f, a2 = 0.f, a3 = 0.f;
    for (unsigned j = s; j < e; ++j) {
        unsigned src = col[j];
        ushort4 v = *(const ushort4*)(xb + (size_t)src * FEAT + lane * 4);
        a0 += bf2f(v.x); a1 += bf2f(v.y); a2 += bf2f(v.z); a3 += bf2f(v.w);
    }
    float r = 1.0f / fmaxf((float)(e - s), 1.0f);
    ushort4 o = make_ushort4(f2bf(a0 * r), f2bf(a1 * r), f2bf(a2 * r), f2bf(a3 * r));
    *(ushort4*)(meanb + (size_t)node * FEAT + lane * 4) = o;
}

// ============================================================================
// Fused GEMM: xbn = bf16( relu([meanb|x] @ [Wl|Wr]^T + bl) + x )
// BM=128, BN=256 (full width), BK=64, 8 waves (2x4 of 64x64).
// A+B staged in LDS via global_load_lds (linear dest, pre-swizzled source),
// ds_read_b128 with st-style XOR swizzle: byte ^= (row&7)<<4  -> conflict-free.
// ============================================================================
__global__ __launch_bounds__(512) void gemm_kernel(const ushort* __restrict__ A0,   // meanb
                                                   const ushort* __restrict__ A1,   // x (bf16), also residual
                                                   const ushort* __restrict__ B0,   // Wl slice [256][256]
                                                   const ushort* __restrict__ B1,   // Wr slice
                                                   const float* __restrict__ bias,  // bl slice [256]
                                                   ushort* __restrict__ xbn) {      // next-layer x
    __shared__ ushort As[128 * 64];   // 16 KB
    __shared__ ushort Bs[256 * 64];   // 32 KB

    const int tid  = threadIdx.x;
    const int lane = tid & 63;
    const int wid  = tid >> 6;          // 0..7
    const int wr   = wid >> 2;          // 0..1  (row half)
    const int wc   = wid & 3;           // 0..3  (col quarter)
    const int row0 = blockIdx.x * 128;

    v4f acc[4][4] = {};

    // staging decomposition: slot s covers rows [s*8, s*8+8), 8 lanes per row
    const int lr8 = lane >> 3;          // row within slot
    const int cb  = (lane & 7) << 4;    // byte col within 128B row

    // fragment decomposition
    const int fr = lane & 15;
    const int lk = (lane >> 4) << 3;    // k offset in elems: 0,8,16,24

    #pragma unroll 1
    for (int kt = 0; kt < 8; ++kt) {
        const ushort* A = (kt < 4) ? A0 : A1;
        const ushort* B = (kt < 4) ? B0 : B1;
        const int kbase = (kt & 3) * 64;

        // stage A tile [128][64]: 16 slots, 2 per wave
        #pragma unroll
        for (int t = 0; t < 2; ++t) {
            int s = wid * 2 + t;
            int r = s * 8 + lr8;
            int grow = row0 + r; grow = grow < N_NODES ? grow : N_NODES - 1;
            int scb = cb ^ ((r & 7) << 4);               // inverse-swizzled source col
            gload16(A + (size_t)grow * FEAT + kbase + (scb >> 1), &As[s * 512]);
        }
        // stage B tile [256][64]: 32 slots, 4 per wave
        #pragma unroll
        for (int t = 0; t < 4; ++t) {
            int s = wid * 4 + t;
            int r = s * 8 + lr8;
            int scb = cb ^ ((r & 7) << 4);
            gload16(B + (size_t)r * FEAT + kbase + (scb >> 1), &Bs[s * 512]);
        }
        __syncthreads();    // drains vmcnt (global_load_lds) per compiler semantics

        #pragma unroll
        for (int kk = 0; kk < 2; ++kk) {
            const int cbk = (kk * 32 + lk) * 2;          // byte col of this frag
            v8s a[4], b[4];
            #pragma unroll
            for (int i = 0; i < 4; ++i) {
                int ra = wr * 64 + i * 16 + fr;
                a[i] = *(const v8s*)((const char*)As + ra * 128 + (cbk ^ ((ra & 7) << 4)));
            }
            #pragma unroll
            for (int j = 0; j < 4; ++j) {
                int rb = wc * 64 + j * 16 + fr;
                b[j] = *(const v8s*)((const char*)Bs + rb * 128 + (cbk ^ ((rb & 7) << 4)));
            }
            #pragma unroll
            for (int i = 0; i < 4; ++i)
                #pragma unroll
                for (int j = 0; j < 4; ++j)
                    acc[i][j] = __builtin_amdgcn_mfma_f32_16x16x32_bf16(a[i], b[j], acc[i][j], 0, 0, 0);
        }
        __syncthreads();    // before next tile overwrites LDS
    }

    // epilogue: C/D layout col=lane&15, row=(lane>>4)*4+reg
    const int orow = (lane >> 4) * 4;
    const int ocol = lane & 15;
    #pragma unroll
    for (int j = 0; j < 4; ++j) {
        int colg = wc * 64 + j * 16 + ocol;
        float bv = bias[colg];
        #pragma unroll
        for (int i = 0; i < 4; ++i) {
            int rbase = row0 + wr * 64 + i * 16 + orow;
            #pragma unroll
            for (int r = 0; r < 4; ++r) {
                int row = rbase + r;
                if (row < N_NODES) {
                    size_t idx = (size_t)row * FEAT + colg;
                    float v = fmaxf(acc[i][j][r] + bv, 0.0f) + bf2f(A1[idx]);
                    xbn[idx] = f2bf(v);
                }
            }
        }
    }
}

// ---- per-graph per-feature online softmax aggregation (bf16 input) ----
__global__ __launch_bounds__(256) void smax_kernel(const ushort* __restrict__ xb,
                                                   const unsigned* __restrict__ gs,
                                                   const unsigned* __restrict__ ge,
                                                   const float* __restrict__ t,
                                                   float* __restrict__ out) {
    int g = blockIdx.x;
    int f = threadIdx.x;
    unsigned s = gs[g], e = ge[g];
    float tv = t[0];
    float m = -INFINITY, den = 0.f, acc = 0.f;
    if (s < e) {
        for (unsigned n = s; n < e; ++n) {
            float xv = bf2f(xb[(size_t)n * FEAT + f]);
            float sc = tv * xv;
            float mn = fmaxf(m, sc);
            float scale = expf(m - mn);     // 0 on first iter (m = -inf)
            float w = expf(sc - mn);
            den = den * scale + w;
            acc = acc * scale + w * xv;
            m = mn;
        }
        out[(size_t)g * FEAT + f] = acc / fmaxf(den, 1e-16f);
    } else {
        out[(size_t)g * FEAT + f] = 0.f;   // empty segment -> 0 per reference
    }
}

extern "C" void kernel_launch(void* const* d_in, const int* in_sizes, int n_in,
                              void* d_out, int out_size, void* d_ws, size_t ws_size,
                              hipStream_t stream) {
    const float* x     = (const float*)d_in[0];
    const int*   ei    = (const int*)d_in[1];    // [2, E]: row0=src, row1=dst
    const int*   batch = (const int*)d_in[2];
    const float* Wl    = (const float*)d_in[3];  // [L, F, F]
    const float* bl    = (const float*)d_in[4];  // [L, F]
    const float* Wr    = (const float*)d_in[5];  // [L, F, F]
    const float* t     = (const float*)d_in[6];  // [1]
    float* out = (float*)d_out;

    const size_t NF2 = (size_t)N_NODES * FEAT * 2;   // 51,200,000
    const size_t WSZ = (size_t)N_LAYERS * FEAT * FEAT * 2;

    char* ws = (char*)d_ws;
    size_t off = 0;
    ushort* xb0   = (ushort*)(ws + off); off += NF2;
    ushort* xb1   = (ushort*)(ws + off); off += NF2;
    ushort* meanb = (ushort*)(ws + off); off += NF2;
    ushort* wlb   = (ushort*)(ws + off); off += WSZ;
    ushort* wrb   = (ushort*)(ws + off); off += WSZ;
    unsigned* degu   = (unsigned*)(ws + off); off += (size_t)N_NODES * 4;
    unsigned* excl   = (unsigned*)(ws + off); off += (size_t)N_NODES * 4;
    unsigned* bsum   = (unsigned*)(ws + off); off += 128 * 4;
    unsigned* rowptr = (unsigned*)(ws + off); off += (size_t)(N_NODES + 1) * 4;
    unsigned* cursor = (unsigned*)(ws + off); off += (size_t)N_NODES * 4;
    unsigned* col    = (unsigned*)(ws + off); off += (size_t)N_EDGES * 4;
    unsigned* gs     = (unsigned*)(ws + off); off += (size_t)N_GRAPHS * 4;
    unsigned* ge     = (unsigned*)(ws + off); off += (size_t)N_GRAPHS * 4;

    hipMemsetAsync(degu, 0, (size_t)N_NODES * 4, stream);
    hipMemsetAsync(gs, 0xFF, (size_t)N_GRAPHS * 4, stream);
    hipMemsetAsync(ge, 0, (size_t)N_GRAPHS * 4, stream);

    init_kernel<<<(N_NODES * FEAT / 4 + 255) / 256, 256, 0, stream>>>(x, xb0);
    wconv_kernel<<<(N_LAYERS * FEAT * FEAT / 4 + 255) / 256, 256, 0, stream>>>(Wl, Wr, wlb, wrb);

    // CSR build
    const int NB_SCAN = (N_NODES + SCAN_B - 1) / SCAN_B;   // 98
    hist_kernel<<<(N_EDGES + 255) / 256, 256, 0, stream>>>(ei + N_EDGES, degu);
    scan_blocks<<<NB_SCAN, SCAN_B, 0, stream>>>(degu, excl, bsum);
    scan_tops<<<1, 1, 0, stream>>>(bsum, NB_SCAN);
    finalize_rowptr<<<(N_NODES + 256) / 256, 256, 0, stream>>>(excl, bsum, rowptr, cursor);
    scatter_kernel<<<(N_EDGES + 255) / 256, 256, 0, stream>>>(ei, cursor, col);

    bounds_kernel<<<(N_NODES + 255) / 256, 256, 0, stream>>>(batch, gs, ge);

    ushort* cur = xb0;
    ushort* nxt = xb1;
    for (int l = 0; l < N_LAYERS; ++l) {
        agg_csr<<<(N_NODES + 3) / 4, 256, 0, stream>>>(rowptr, col, cur, meanb);
        gemm_kernel<<<dim3((N_NODES + 127) / 128), 512, 0, stream>>>(
            meanb, cur,
            wlb + (size_t)l * FEAT * FEAT, wrb + (size_t)l * FEAT * FEAT,
            bl + (size_t)l * FEAT, nxt);
        ushort* tmp = cur; cur = nxt; nxt = tmp;
    }

    smax_kernel<<<N_GRAPHS, 256, 0, stream>>>(cur, gs, ge, t, out);
}

// Round 4
// 929.869 us; speedup vs baseline: 8.5307x; 1.0922x over previous
//
#include <hip/hip_runtime.h>
#include <hip/hip_bf16.h>

#define N_NODES  100000
#define N_EDGES  300000
#define FEAT     256
#define N_GRAPHS 500
#define N_LAYERS 6
#define SCAN_B   1024

typedef __attribute__((ext_vector_type(8))) short v8s;   // 8 x bf16 bits (4 VGPRs)
typedef __attribute__((ext_vector_type(4))) float v4f;   // MFMA accumulator

__device__ __forceinline__ unsigned short f2bf(float f) {
    unsigned u = __float_as_uint(f);
    unsigned r = u + 0x7fffu + ((u >> 16) & 1u);   // RNE
    return (unsigned short)(r >> 16);
}
__device__ __forceinline__ float bf2f(unsigned short b) {
    return __uint_as_float(((unsigned)b) << 16);
}

__device__ __forceinline__ void gload16(const ushort* g, ushort* l) {
    __builtin_amdgcn_global_load_lds((const __attribute__((address_space(1))) void*)g,
                                     (__attribute__((address_space(3))) void*)l,
                                     16, 0, 0);
}

// ---- init: x (f32) -> xb (bf16) ----
__global__ __launch_bounds__(256) void init_kernel(const float* __restrict__ x,
                                                   ushort* __restrict__ xb) {
    int i = blockIdx.x * 256 + threadIdx.x;           // per 4 elements
    if ((size_t)i * 4 >= (size_t)N_NODES * FEAT) return;
    float4 v = ((const float4*)x)[i];
    ((ushort4*)xb)[i] = make_ushort4(f2bf(v.x), f2bf(v.y), f2bf(v.z), f2bf(v.w));
}

// ---- weights f32 -> bf16, all layers at once ----
__global__ __launch_bounds__(256) void wconv_kernel(const float* __restrict__ Wl,
                                                    const float* __restrict__ Wr,
                                                    ushort* __restrict__ wlb,
                                                    ushort* __restrict__ wrb) {
    int i = blockIdx.x * 256 + threadIdx.x;           // per 4 elements
    if ((size_t)i * 4 >= (size_t)N_LAYERS * FEAT * FEAT) return;
    float4 a = ((const float4*)Wl)[i];
    float4 b = ((const float4*)Wr)[i];
    ((ushort4*)wlb)[i] = make_ushort4(f2bf(a.x), f2bf(a.y), f2bf(a.z), f2bf(a.w));
    ((ushort4*)wrb)[i] = make_ushort4(f2bf(b.x), f2bf(b.y), f2bf(b.z), f2bf(b.w));
}

// ================= CSR construction (counting sort by dst) =================

__global__ __launch_bounds__(256) void hist_kernel(const int* __restrict__ dst,
                                                   unsigned* __restrict__ degu) {
    int e = blockIdx.x * 256 + threadIdx.x;
    if (e < N_EDGES) atomicAdd(&degu[dst[e]], 1u);
}

__global__ __launch_bounds__(SCAN_B) void scan_blocks(const unsigned* __restrict__ degu,
                                                      unsigned* __restrict__ excl,
                                                      unsigned* __restrict__ bsum) {
    __shared__ unsigned tmp[SCAN_B];
    int i = blockIdx.x * SCAN_B + threadIdx.x;
    unsigned v = (i < N_NODES) ? degu[i] : 0u;
    tmp[threadIdx.x] = v;
    __syncthreads();
    for (int off = 1; off < SCAN_B; off <<= 1) {
        unsigned add = (threadIdx.x >= off) ? tmp[threadIdx.x - off] : 0u;
        __syncthreads();
        tmp[threadIdx.x] += add;
        __syncthreads();
    }
    if (i < N_NODES) excl[i] = tmp[threadIdx.x] - v;
    if (threadIdx.x == SCAN_B - 1) bsum[blockIdx.x] = tmp[SCAN_B - 1];
}

__global__ void scan_tops(unsigned* __restrict__ bsum, int nb) {
    unsigned run = 0;
    for (int b = 0; b < nb; ++b) { unsigned t = bsum[b]; bsum[b] = run; run += t; }
}

__global__ __launch_bounds__(256) void finalize_rowptr(const unsigned* __restrict__ excl,
                                                       const unsigned* __restrict__ bsum,
                                                       unsigned* __restrict__ rowptr,
                                                       unsigned* __restrict__ cursor) {
    int i = blockIdx.x * 256 + threadIdx.x;
    if (i < N_NODES) {
        unsigned v = excl[i] + bsum[i / SCAN_B];
        rowptr[i] = v;
        cursor[i] = v;
    }
    if (i == N_NODES) rowptr[N_NODES] = N_EDGES;
}

__global__ __launch_bounds__(256) void scatter_kernel(const int* __restrict__ ei,
                                                      unsigned* __restrict__ cursor,
                                                      unsigned* __restrict__ col) {
    int e = blockIdx.x * 256 + threadIdx.x;
    if (e >= N_EDGES) return;
    int d = ei[N_EDGES + e];
    unsigned p = atomicAdd(&cursor[d], 1u);
    col[p] = (unsigned)ei[e];
}

// ---- per-graph [start,end) bounds from sorted batch: boundary detection ----
__global__ __launch_bounds__(256) void bounds_kernel(const int* __restrict__ batch,
                                                     unsigned* __restrict__ gs,
                                                     unsigned* __restrict__ ge) {
    int i = blockIdx.x * 256 + threadIdx.x;
    if (i >= N_NODES) return;
    int g = batch[i];
    int gp = (i == 0) ? -1 : batch[i - 1];
    if (g != gp) gs[g] = (unsigned)i;
    int gn = (i == N_NODES - 1) ? -1 : batch[i + 1];
    if (g != gn) ge[g] = (unsigned)(i + 1);
}

// ---- CSR mean-aggregate: one wave per node, 4 feats/lane, no atomics ----
__global__ __launch_bounds__(256) void agg_csr(const unsigned* __restrict__ rowptr,
                                               const unsigned* __restrict__ col,
                                               const ushort* __restrict__ xb,
                                               ushort* __restrict__ meanb) {
    int node = blockIdx.x * 4 + (threadIdx.x >> 6);
    int lane = threadIdx.x & 63;
    if (node >= N_NODES) return;
    unsigned s = rowptr[node], e = rowptr[node + 1];
    float a0 = 0.f, a1 = 0.f, a2 = 0.f, a3 = 0.f;
    for (unsigned j = s; j < e; ++j) {
        unsigned src = col[j];
        ushort4 v = *(const ushort4*)(xb + (size_t)src * FEAT + lane * 4);
        a0 += bf2f(v.x); a1 += bf2f(v.y); a2 += bf2f(v.z); a3 += bf2f(v.w);
    }
    float r = 1.0f / fmaxf((float)(e - s), 1.0f);
    ushort4 o = make_ushort4(f2bf(a0 * r), f2bf(a1 * r), f2bf(a2 * r), f2bf(a3 * r));
    *(ushort4*)(meanb + (size_t)node * FEAT + lane * 4) = o;
}

// ============================================================================
// Fused GEMM: xbn = bf16( relu([meanb|x] @ [Wl|Wr]^T + bl) + x )
// BM=128, BN=256, BK=32, 8 waves (2x4 of 64x64), double-buffered LDS,
// 2-phase pipeline: issue next tile's global_load_lds before computing current.
// LDS layout: 2 rows (64B each) packed per 128B line, XOR-swizzled
// (byte ^= (line&7)<<4) -> 2-way bank alias on ds_read_b128 (free).
// Stage side uses the inverse (= same) swizzle on the GLOBAL source address,
// LDS dest stays linear (global_load_lds requirement).
// ============================================================================
#define ATILE 4096   // ushorts: 128 rows x 32 elems = 8 KB
#define BTILE 8192   // ushorts: 256 rows x 32 elems = 16 KB

__global__ __launch_bounds__(512) void gemm_kernel(const ushort* __restrict__ A0,   // meanb
                                                   const ushort* __restrict__ A1,   // x (bf16), also residual
                                                   const ushort* __restrict__ B0,   // Wl slice [256][256]
                                                   const ushort* __restrict__ B1,   // Wr slice
                                                   const float* __restrict__ bias,  // bl slice [256]
                                                   ushort* __restrict__ xbn) {      // next-layer x
    __shared__ ushort As[2][ATILE];   // 2 x 8 KB
    __shared__ ushort Bs[2][BTILE];   // 2 x 16 KB

    const int tid  = threadIdx.x;
    const int lane = tid & 63;
    const int wid  = tid >> 6;          // 0..7
    const int wr   = wid >> 2;          // 0..1  (row half of 128)
    const int wc   = wid & 3;           // 0..3  (col quarter of 256)
    const int row0 = blockIdx.x * 128;

    v4f acc[4][4] = {};

    const int fr  = lane & 15;
    const int cbk = (lane >> 4) << 4;   // frag byte col within 64B row: 0,16,32,48

    // ---- staging address precompute (kt-invariant parts) ----
    // A: chunk tid covers LDS bytes [tid*16, tid*16+16)
    const int pA  = tid >> 3;
    const int w0A = ((tid & 7) ^ (pA & 7)) << 4;
    int rA = row0 + 2 * pA + (w0A >> 6);
    rA = rA < N_NODES ? rA : N_NODES - 1;
    const int cbA = w0A & 63;
    // B: chunks tid and tid+512
    const int pB0  = tid >> 3;
    const int w0B0 = ((tid & 7) ^ (pB0 & 7)) << 4;
    const int rB0  = 2 * pB0 + (w0B0 >> 6);
    const int cbB0 = w0B0 & 63;
    const int c1   = tid + 512;
    const int pB1  = c1 >> 3;
    const int w0B1 = ((c1 & 7) ^ (pB1 & 7)) << 4;
    const int rB1  = 2 * pB1 + (w0B1 >> 6);
    const int cbB1 = w0B1 & 63;

    #define STAGE(buf, kt) do {                                                   \
        const ushort* Asrc = ((kt) < 8) ? A0 : A1;                                \
        const ushort* Bsrc = ((kt) < 8) ? B0 : B1;                                \
        const int kb = ((kt) & 7) * 32;                                           \
        gload16(Asrc + (size_t)rA  * FEAT + kb + (cbA  >> 1), &As[buf][tid * 8]); \
        gload16(Bsrc + (size_t)rB0 * FEAT + kb + (cbB0 >> 1), &Bs[buf][tid * 8]); \
        gload16(Bsrc + (size_t)rB1 * FEAT + kb + (cbB1 >> 1), &Bs[buf][(size_t)c1 * 8]); \
    } while (0)

    #define FRAG(basePtr, row) \
        (*(const v8s*)((const char*)(basePtr) + (((row) >> 1) * 128 + \
            ((((row) & 1) << 6) + cbk) ^ ((((row) >> 1) & 7) << 4))))

    #define COMPUTE(buf) do {                                                     \
        v8s a[4], b[4];                                                           \
        _Pragma("unroll")                                                         \
        for (int i = 0; i < 4; ++i) a[i] = FRAG(As[buf], wr * 64 + i * 16 + fr);  \
        _Pragma("unroll")                                                         \
        for (int j = 0; j < 4; ++j) b[j] = FRAG(Bs[buf], wc * 64 + j * 16 + fr);  \
        _Pragma("unroll")                                                         \
        for (int i = 0; i < 4; ++i)                                               \
            _Pragma("unroll")                                                     \
            for (int j = 0; j < 4; ++j)                                           \
                acc[i][j] = __builtin_amdgcn_mfma_f32_16x16x32_bf16(a[i], b[j], acc[i][j], 0, 0, 0); \
    } while (0)

    STAGE(0, 0);
    __syncthreads();
    #pragma unroll 1
    for (int kt = 0; kt < 15; ++kt) {
        STAGE((kt + 1) & 1, kt + 1);   // issue next tile: in flight under compute
        COMPUTE(kt & 1);
        __syncthreads();               // drains vmcnt -> next buffer ready; guards reuse
    }
    COMPUTE(1);                        // kt = 15

    // epilogue: C/D layout col=lane&15, row=(lane>>4)*4+reg
    const int orow = (lane >> 4) * 4;
    const int ocol = lane & 15;
    #pragma unroll
    for (int j = 0; j < 4; ++j) {
        int colg = wc * 64 + j * 16 + ocol;
        float bv = bias[colg];
        #pragma unroll
        for (int i = 0; i < 4; ++i) {
            int rbase = row0 + wr * 64 + i * 16 + orow;
            #pragma unroll
            for (int r = 0; r < 4; ++r) {
                int row = rbase + r;
                if (row < N_NODES) {
                    size_t idx = (size_t)row * FEAT + colg;
                    float v = fmaxf(acc[i][j][r] + bv, 0.0f) + bf2f(A1[idx]);
                    xbn[idx] = f2bf(v);
                }
            }
        }
    }
    #undef STAGE
    #undef FRAG
    #undef COMPUTE
}

// ---- per-graph per-feature online softmax aggregation (bf16 input) ----
__global__ __launch_bounds__(256) void smax_kernel(const ushort* __restrict__ xb,
                                                   const unsigned* __restrict__ gs,
                                                   const unsigned* __restrict__ ge,
                                                   const float* __restrict__ t,
                                                   float* __restrict__ out) {
    int g = blockIdx.x;
    int f = threadIdx.x;
    unsigned s = gs[g], e = ge[g];
    float tv = t[0];
    float m = -INFINITY, den = 0.f, acc = 0.f;
    if (s < e) {
        for (unsigned n = s; n < e; ++n) {
            float xv = bf2f(xb[(size_t)n * FEAT + f]);
            float sc = tv * xv;
            float mn = fmaxf(m, sc);
            float scale = expf(m - mn);     // 0 on first iter (m = -inf)
            float w = expf(sc - mn);
            den = den * scale + w;
            acc = acc * scale + w * xv;
            m = mn;
        }
        out[(size_t)g * FEAT + f] = acc / fmaxf(den, 1e-16f);
    } else {
        out[(size_t)g * FEAT + f] = 0.f;   // empty segment -> 0 per reference
    }
}

extern "C" void kernel_launch(void* const* d_in, const int* in_sizes, int n_in,
                              void* d_out, int out_size, void* d_ws, size_t ws_size,
                              hipStream_t stream) {
    const float* x     = (const float*)d_in[0];
    const int*   ei    = (const int*)d_in[1];    // [2, E]: row0=src, row1=dst
    const int*   batch = (const int*)d_in[2];
    const float* Wl    = (const float*)d_in[3];  // [L, F, F]
    const float* bl    = (const float*)d_in[4];  // [L, F]
    const float* Wr    = (const float*)d_in[5];  // [L, F, F]
    const float* t     = (const float*)d_in[6];  // [1]
    float* out = (float*)d_out;

    const size_t NF2 = (size_t)N_NODES * FEAT * 2;   // 51,200,000
    const size_t WSZ = (size_t)N_LAYERS * FEAT * FEAT * 2;

    char* ws = (char*)d_ws;
    size_t off = 0;
    ushort* xb0   = (ushort*)(ws + off); off += NF2;
    ushort* xb1   = (ushort*)(ws + off); off += NF2;
    ushort* meanb = (ushort*)(ws + off); off += NF2;
    ushort* wlb   = (ushort*)(ws + off); off += WSZ;
    ushort* wrb   = (ushort*)(ws + off); off += WSZ;
    unsigned* degu   = (unsigned*)(ws + off); off += (size_t)N_NODES * 4;
    unsigned* excl   = (unsigned*)(ws + off); off += (size_t)N_NODES * 4;
    unsigned* bsum   = (unsigned*)(ws + off); off += 128 * 4;
    unsigned* rowptr = (unsigned*)(ws + off); off += (size_t)(N_NODES + 1) * 4;
    unsigned* cursor = (unsigned*)(ws + off); off += (size_t)N_NODES * 4;
    unsigned* col    = (unsigned*)(ws + off); off += (size_t)N_EDGES * 4;
    unsigned* gs     = (unsigned*)(ws + off); off += (size_t)N_GRAPHS * 4;
    unsigned* ge     = (unsigned*)(ws + off); off += (size_t)N_GRAPHS * 4;

    hipMemsetAsync(degu, 0, (size_t)N_NODES * 4, stream);
    hipMemsetAsync(gs, 0xFF, (size_t)N_GRAPHS * 4, stream);
    hipMemsetAsync(ge, 0, (size_t)N_GRAPHS * 4, stream);

    init_kernel<<<(N_NODES * FEAT / 4 + 255) / 256, 256, 0, stream>>>(x, xb0);
    wconv_kernel<<<(N_LAYERS * FEAT * FEAT / 4 + 255) / 256, 256, 0, stream>>>(Wl, Wr, wlb, wrb);

    // CSR build
    const int NB_SCAN = (N_NODES + SCAN_B - 1) / SCAN_B;   // 98
    hist_kernel<<<(N_EDGES + 255) / 256, 256, 0, stream>>>(ei + N_EDGES, degu);
    scan_blocks<<<NB_SCAN, SCAN_B, 0, stream>>>(degu, excl, bsum);
    scan_tops<<<1, 1, 0, stream>>>(bsum, NB_SCAN);
    finalize_rowptr<<<(N_NODES + 256) / 256, 256, 0, stream>>>(excl, bsum, rowptr, cursor);
    scatter_kernel<<<(N_EDGES + 255) / 256, 256, 0, stream>>>(ei, cursor, col);

    bounds_kernel<<<(N_NODES + 255) / 256, 256, 0, stream>>>(batch, gs, ge);

    ushort* cur = xb0;
    ushort* nxt = xb1;
    for (int l = 0; l < N_LAYERS; ++l) {
        agg_csr<<<(N_NODES + 3) / 4, 256, 0, stream>>>(rowptr, col, cur, meanb);
        gemm_kernel<<<dim3((N_NODES + 127) / 128), 512, 0, stream>>>(
            meanb, cur,
            wlb + (size_t)l * FEAT * FEAT, wrb + (size_t)l * FEAT * FEAT,
            bl + (size_t)l * FEAT, nxt);
        ushort* tmp = cur; cur = nxt; nxt = tmp;
    }

    smax_kernel<<<N_GRAPHS, 256, 0, stream>>>(cur, gs, ge, t, out);
}